// Round 10
// baseline (84.551 us; speedup 1.0000x reference)
//
#include <hip/hip_runtime.h>

// TokenTreeModel: out[b,t,v] = bias + sum_{d,c: tok[b,t,d,c]==v} cnt[b,t,d,c]*w[d]
// B=2, T=256, DEPTH=8, VOCAB=32000, NCHILD=64
//
// Fused single-kernel design: one block per (row, vocab-half).
//   - LDS accumulator of 16000 floats (62.5 KiB) -> 2 blocks/CU, 32 waves/CU
//   - entry loads issued FIRST (latency hides under LDS zeroing)
//   - LDS atomicAdd scatter (512 entries, filter by half)
//   - stream out bias + acc with coalesced nontemporal 16B stores.
// Global traffic = 65.5 MB write + ~2 MB read (ideal); no global atomics.
//
// NOTE: __builtin_nontemporal_store requires a native clang vector type,
// not HIP's float4 (a HIP_vector_type class) -> use ext_vector_type(4).

#define BB 2
#define TT 256
#define DEPTHD 8
#define VOCABV 32000
#define NCHILDC 64
#define HALF (VOCABV / 2)            // 16000
#define ENTRIES (DEPTHD * NCHILDC)   // 512 per row

typedef float f32x4 __attribute__((ext_vector_type(4)));

__global__ __launch_bounds__(1024, 1) void tt_fused(
    const int* __restrict__ tokens,
    const float* __restrict__ counts,
    const float* __restrict__ w,
    const float* __restrict__ bias,
    float* __restrict__ out)
{
    __shared__ float acc[HALF];               // 64,000 B
    const int bid  = blockIdx.x;
    const int row  = bid >> 1;                // b*T + t
    const int half = bid & 1;                 // vocab half: [0,16000) or [16000,32000)
    const int tid  = threadIdx.x;

    // Issue this row's entry loads FIRST so HBM latency hides under LDS zeroing.
    int tok = 0;
    float cnt = 0.f;
    const bool active = tid < ENTRIES;
    if (active) {
        const int idx = row * ENTRIES + tid;
        tok = __builtin_nontemporal_load(&tokens[idx]);
        cnt = __builtin_nontemporal_load(&counts[idx]);
    }
    const float wd = w[tid >> 6 & 7];         // d = tid/NCHILD (valid for tid<512)
    const float b  = bias[0];

    // Phase 1: zero the LDS accumulator (16B stores, 4000 x 16B).
    f32x4* acc4 = reinterpret_cast<f32x4*>(acc);
    #pragma unroll
    for (int i = tid; i < HALF / 4; i += 1024)
        acc4[i] = (f32x4){0.f, 0.f, 0.f, 0.f};
    __syncthreads();

    // Phase 2: scatter this row's 512 (token, count) pairs into LDS.
    if (active) {
        const int local = tok - half * HALF;
        if ((unsigned)local < (unsigned)HALF)
            atomicAdd(&acc[local], cnt * wd);
    }
    __syncthreads();

    // Phase 3: stream half-row to global with bias added (nontemporal 16B).
    f32x4* o4 = reinterpret_cast<f32x4*>(out + (size_t)row * VOCABV + half * HALF);
    #pragma unroll
    for (int i = tid; i < HALF / 4; i += 1024) {
        f32x4 v = acc4[i];
        v += b;  // vector splat add
        __builtin_nontemporal_store(v, &o4[i]);
    }
}

extern "C" void kernel_launch(void* const* d_in, const int* in_sizes, int n_in,
                              void* d_out, int out_size, void* d_ws, size_t ws_size,
                              hipStream_t stream) {
    const int*   tokens = (const int*)d_in[0];
    const float* counts = (const float*)d_in[1];
    const float* w      = (const float*)d_in[2];
    const float* bias   = (const float*)d_in[3];
    float* out = (float*)d_out;

    const int nblocks = BB * TT * 2;  // 512 rows x 2 halves = 1024
    tt_fused<<<nblocks, 1024, 0, stream>>>(tokens, counts, w, bias, out);
}

// Round 11
// 82.947 us; speedup vs baseline: 1.0193x; 1.0193x over previous
//
#include <hip/hip_runtime.h>

// TokenTreeModel: out[b,t,v] = bias + sum_{d,c: tok[b,t,d,c]==v} cnt[b,t,d,c]*w[d]
// B=2, T=256, DEPTH=8, VOCAB=32000, NCHILD=64
//
// Quarter-vocab fused design: one block per (row, vocab-quarter).
//   - 2048 blocks x 512 threads, LDS acc = 8000 floats (32 KiB)
//   - 4 blocks/CU concurrent (32 waves/CU), finer tail than 64KB halves
//   - each thread owns exactly 1 of the row's 512 entries (d = tid>>6)
//   - LDS atomicAdd scatter (filter by quarter), nontemporal 16B out stream.
// Global traffic = 65.5 MB write + ~8 MB read; no global atomics.

#define BB 2
#define TT 256
#define DEPTHD 8
#define VOCABV 32000
#define NCHILDC 64
#define QUARTER (VOCABV / 4)         // 8000
#define ENTRIES (DEPTHD * NCHILDC)   // 512 per row
#define QV4 (QUARTER / 4)            // 2000 f32x4 slots

typedef float f32x4 __attribute__((ext_vector_type(4)));

__global__ __launch_bounds__(512, 2) void tt_fused_q(
    const int* __restrict__ tokens,
    const float* __restrict__ counts,
    const float* __restrict__ w,
    const float* __restrict__ bias,
    float* __restrict__ out)
{
    __shared__ float acc[QUARTER];            // 32,000 B
    const int bid = blockIdx.x;
    const int row = bid >> 2;                 // b*T + t
    const int q   = bid & 3;                  // vocab quarter
    const int tid = threadIdx.x;              // [0,512)

    // Issue this row's entry loads first (latency hides under LDS zeroing).
    // Regular loads: 4 quarter-blocks re-read the same 4 KB -> let L2 serve.
    const int idx = row * ENTRIES + tid;
    const int tok = tokens[idx];
    const float cnt = counts[idx];
    const float wd = w[tid >> 6];             // d = tid/NCHILD, in [0,8)
    const float b  = bias[0];

    // Phase 1: zero the LDS accumulator (2000 x 16B).
    f32x4* acc4 = reinterpret_cast<f32x4*>(acc);
    #pragma unroll
    for (int i = tid; i < QV4; i += 512)
        acc4[i] = (f32x4){0.f, 0.f, 0.f, 0.f};
    __syncthreads();

    // Phase 2: scatter this row's 512 (token, count) pairs into LDS.
    const int local = tok - q * QUARTER;
    if ((unsigned)local < (unsigned)QUARTER)
        atomicAdd(&acc[local], cnt * wd);
    __syncthreads();

    // Phase 3: stream quarter-row to global with bias added (nontemporal 16B).
    f32x4* o4 = reinterpret_cast<f32x4*>(out + (size_t)row * VOCABV + q * QUARTER);
    #pragma unroll
    for (int i = tid; i < QV4; i += 512) {
        f32x4 v = acc4[i];
        v += b;
        __builtin_nontemporal_store(v, &o4[i]);
    }
}

extern "C" void kernel_launch(void* const* d_in, const int* in_sizes, int n_in,
                              void* d_out, int out_size, void* d_ws, size_t ws_size,
                              hipStream_t stream) {
    const int*   tokens = (const int*)d_in[0];
    const float* counts = (const float*)d_in[1];
    const float* w      = (const float*)d_in[2];
    const float* bias   = (const float*)d_in[3];
    float* out = (float*)d_out;

    const int nblocks = BB * TT * 4;  // 512 rows x 4 quarters = 2048
    tt_fused_q<<<nblocks, 512, 0, stream>>>(tokens, counts, w, bias, out);
}